// Round 1
// baseline (198.398 us; speedup 1.0000x reference)
//
#include <hip/hip_runtime.h>
#include <stdint.h>

typedef unsigned short u16;
typedef __attribute__((ext_vector_type(8))) short short8;
typedef __attribute__((ext_vector_type(4))) float f32x4;

__device__ __forceinline__ float bf2f(u16 u) {
    union { unsigned int i; float f; } v;
    v.i = ((unsigned int)u) << 16;
    return v.f;
}
__device__ __forceinline__ u16 f2bf(float f) {
    union { float f; unsigned int i; } v; v.f = f;
    unsigned int b = v.i;
    return (u16)((b + 0x7FFFu + ((b >> 16) & 1u)) >> 16);
}

// ---------------------------------------------------------------------------
// Kernel 1: weight convert fp32 -> bf16, transposed: Wt[n][k] = W[k][n]
// grid (4,4,4 weights), block 256
// ---------------------------------------------------------------------------
__global__ __launch_bounds__(256) void wprep(
    const float* __restrict__ W0, const float* __restrict__ W1,
    const float* __restrict__ W2, const float* __restrict__ W3,
    u16* __restrict__ T0, u16* __restrict__ T1,
    u16* __restrict__ T2, u16* __restrict__ T3)
{
    const float* W = blockIdx.z == 0 ? W0 : blockIdx.z == 1 ? W1 : blockIdx.z == 2 ? W2 : W3;
    u16*        T  = blockIdx.z == 0 ? T0 : blockIdx.z == 1 ? T1 : blockIdx.z == 2 ? T2 : T3;
    __shared__ u16 ts[64][65];
    int k0 = blockIdx.x * 64, n0 = blockIdx.y * 64;
    int t = threadIdx.x;
    int r = t >> 2, cq = (t & 3) * 16;
    const float4* src = reinterpret_cast<const float4*>(W + (k0 + r) * 256 + n0 + cq);
    for (int u = 0; u < 4; ++u) {
        float4 v = src[u];
        int c = cq + u * 4;
        ts[r][c + 0] = f2bf(v.x); ts[r][c + 1] = f2bf(v.y);
        ts[r][c + 2] = f2bf(v.z); ts[r][c + 3] = f2bf(v.w);
    }
    __syncthreads();
    u16* dst = T + (n0 + r) * 256 + k0 + cq;
    for (int u = 0; u < 16; ++u) dst[u] = ts[cq + u][r];
}

// ---------------------------------------------------------------------------
// Kernel 2: projection GEMM, A fp32 [16384,256] @ Wt' (bf16, pre-transposed)
// + bias -> C bf16 [16384,256].  grid (128, 2, 3), block 256 (4 waves).
// 128x128 tile, BK=64, mfma_f32_16x16x32_bf16.
// LDS rows padded to 72 bf16 (144 B): keeps 16B alignment, breaks 32-bank stride.
// ---------------------------------------------------------------------------
__global__ __launch_bounds__(256) void gemm_proj(
    const float* __restrict__ Q, const float* __restrict__ K,
    const u16* __restrict__ Wtq, const u16* __restrict__ Wtk, const u16* __restrict__ Wtv,
    const float* __restrict__ bq, const float* __restrict__ bk, const float* __restrict__ bv,
    u16* __restrict__ Qh, u16* __restrict__ Kh, u16* __restrict__ Vh)
{
    int z = blockIdx.z;
    const float* A    = (z == 0) ? Q   : K;
    const u16*   Wt   = (z == 0) ? Wtq : (z == 1) ? Wtk : Wtv;
    const float* bias = (z == 0) ? bq  : (z == 1) ? bk  : bv;
    u16*         C    = (z == 0) ? Qh  : (z == 1) ? Kh  : Vh;

    __shared__ u16 As[128][72];
    __shared__ u16 Ws[128][72];

    int t = threadIdx.x;
    int lane = t & 63, w = t >> 6;
    int row0 = blockIdx.x * 128, col0 = blockIdx.y * 128;
    int wr = (w >> 1) * 64, wc = (w & 1) * 64;
    int qd = lane >> 4, md = lane & 15;

    f32x4 acc[4][4] = {};

    for (int kt = 0; kt < 256; kt += 64) {
        // stage A tile (128 rows x 64 k) fp32 -> bf16
        {
            int r = t >> 1, half = (t & 1) * 32;
            const float4* src = reinterpret_cast<const float4*>(
                A + (size_t)(row0 + r) * 256 + kt + half);
            u16* dst = &As[r][half];
            for (int u = 0; u < 8; ++u) {
                float4 v = src[u];
                dst[u * 4 + 0] = f2bf(v.x); dst[u * 4 + 1] = f2bf(v.y);
                dst[u * 4 + 2] = f2bf(v.z); dst[u * 4 + 3] = f2bf(v.w);
            }
        }
        // stage Wt tile (128 n-rows x 64 k) bf16 straight copy
        {
            int r = t >> 1, half = (t & 1) * 32;
            const uint4* src = reinterpret_cast<const uint4*>(
                Wt + (size_t)(col0 + r) * 256 + kt + half);
            uint4* dst = reinterpret_cast<uint4*>(&Ws[r][half]);
            dst[0] = src[0]; dst[1] = src[1]; dst[2] = src[2]; dst[3] = src[3];
        }
        __syncthreads();
        for (int ks = 0; ks < 64; ks += 32) {
            short8 af[4], bf[4];
            for (int i = 0; i < 4; ++i)
                af[i] = *reinterpret_cast<const short8*>(&As[wr + i * 16 + md][ks + qd * 8]);
            for (int j = 0; j < 4; ++j)
                bf[j] = *reinterpret_cast<const short8*>(&Ws[wc + j * 16 + md][ks + qd * 8]);
            for (int i = 0; i < 4; ++i)
                for (int j = 0; j < 4; ++j)
                    acc[i][j] = __builtin_amdgcn_mfma_f32_16x16x32_bf16(
                        af[i], bf[j], acc[i][j], 0, 0, 0);
        }
        __syncthreads();
    }
    // epilogue: + bias, store bf16
    for (int i = 0; i < 4; ++i)
        for (int j = 0; j < 4; ++j) {
            int col = col0 + wc + j * 16 + md;
            float b = bias[col];
            for (int r = 0; r < 4; ++r) {
                int row = row0 + wr + i * 16 + qd * 4 + r;
                C[(size_t)row * 256 + col] = f2bf(acc[i][j][r] + b);
            }
        }
}

// ---------------------------------------------------------------------------
// Kernel 3: gather attention. One block (256 thr) per (b,n).
// ---------------------------------------------------------------------------
__global__ __launch_bounds__(256) void attn(
    const u16* __restrict__ Qh, const u16* __restrict__ Kh, const u16* __restrict__ Vh,
    const int* __restrict__ nbr, u16* __restrict__ AVb)
{
    __shared__ u16 Ks[32][264];   // stride 264 bf16 = 528 B (16B-aligned, bank-safe)
    __shared__ u16 Vs[32][264];
    __shared__ float qs[256];
    __shared__ float as_[256];
    __shared__ int ji[32];

    int t = threadIdx.x;
    int row = blockIdx.x;             // b*8192 + n
    int b = row >> 13;
    size_t qbase = (size_t)row * 256;

    qs[t] = bf2f(Qh[qbase + t]);
    if (t < 32) ji[t] = nbr[(size_t)row * 32 + t];
    __syncthreads();

    // gather 32 K rows and 32 V rows (512 B each) into LDS
    {
        int j = t >> 3, seg = t & 7;
        size_t kb = ((size_t)(b << 13) + (size_t)ji[j]) * 256;
        const uint4* ksrc = reinterpret_cast<const uint4*>(Kh + kb);
        const uint4* vsrc = reinterpret_cast<const uint4*>(Vh + kb);
        uint4* kdst = reinterpret_cast<uint4*>(&Ks[j][seg * 32]);
        uint4* vdst = reinterpret_cast<uint4*>(&Vs[j][seg * 32]);
        for (int u = 0; u < 4; ++u) { kdst[u] = ksrc[seg * 4 + u]; vdst[u] = vsrc[seg * 4 + u]; }
    }
    __syncthreads();

    // scores: thread t -> (h = t>>5, j = t&31)
    int h = t >> 5, j = t & 31;
    float e = 0.f;
    for (int c = 0; c < 4; ++c) {
        short8 kv = *reinterpret_cast<const short8*>(&Ks[j][h * 32 + c * 8]);
        for (int u = 0; u < 8; ++u)
            e += qs[h * 32 + c * 8 + u] * bf2f((u16)kv[u]);
    }
    e *= 0.0625f;  // 1/sqrt(256)

    // softmax over the 32 j-lanes of each head
    float m = e;
    for (int off = 16; off; off >>= 1) m = fmaxf(m, __shfl_xor(m, off, 32));
    float p = __expf(e - m);
    float s = p;
    for (int off = 16; off; off >>= 1) s += __shfl_xor(s, off, 32);
    as_[t] = p / s;
    __syncthreads();

    // AV: thread t -> output channel d = t
    int hh = t >> 5;
    float acc = 0.f;
    for (int jj = 0; jj < 32; ++jj)
        acc += as_[hh * 32 + jj] * bf2f(Vs[jj][t]);
    AVb[qbase + t] = f2bf(acc);
}

// ---------------------------------------------------------------------------
// Kernel 4: output GEMM, A bf16 [16384,256] @ Wto + bo -> fp32 out
// ---------------------------------------------------------------------------
__global__ __launch_bounds__(256) void gemm_out(
    const u16* __restrict__ A, const u16* __restrict__ Wt,
    const float* __restrict__ bias, float* __restrict__ Cout)
{
    __shared__ u16 As[128][72];
    __shared__ u16 Ws[128][72];

    int t = threadIdx.x;
    int lane = t & 63, w = t >> 6;
    int row0 = blockIdx.x * 128, col0 = blockIdx.y * 128;
    int wr = (w >> 1) * 64, wc = (w & 1) * 64;
    int qd = lane >> 4, md = lane & 15;

    f32x4 acc[4][4] = {};

    for (int kt = 0; kt < 256; kt += 64) {
        {
            int r = t >> 1, half = (t & 1) * 32;
            const uint4* srcA = reinterpret_cast<const uint4*>(
                A + (size_t)(row0 + r) * 256 + kt + half);
            uint4* dstA = reinterpret_cast<uint4*>(&As[r][half]);
            dstA[0] = srcA[0]; dstA[1] = srcA[1]; dstA[2] = srcA[2]; dstA[3] = srcA[3];
            const uint4* srcW = reinterpret_cast<const uint4*>(
                Wt + (size_t)(col0 + r) * 256 + kt + half);
            uint4* dstW = reinterpret_cast<uint4*>(&Ws[r][half]);
            dstW[0] = srcW[0]; dstW[1] = srcW[1]; dstW[2] = srcW[2]; dstW[3] = srcW[3];
        }
        __syncthreads();
        for (int ks = 0; ks < 64; ks += 32) {
            short8 af[4], bf[4];
            for (int i = 0; i < 4; ++i)
                af[i] = *reinterpret_cast<const short8*>(&As[wr + i * 16 + md][ks + qd * 8]);
            for (int j = 0; j < 4; ++j)
                bf[j] = *reinterpret_cast<const short8*>(&Ws[wc + j * 16 + md][ks + qd * 8]);
            for (int i = 0; i < 4; ++i)
                for (int j = 0; j < 4; ++j)
                    acc[i][j] = __builtin_amdgcn_mfma_f32_16x16x32_bf16(
                        af[i], bf[j], acc[i][j], 0, 0, 0);
        }
        __syncthreads();
    }
    for (int i = 0; i < 4; ++i)
        for (int j = 0; j < 4; ++j) {
            int col = col0 + wc + j * 16 + md;
            float b = bias[col];
            for (int r = 0; r < 4; ++r) {
                int row = row0 + wr + i * 16 + qd * 4 + r;
                Cout[(size_t)row * 256 + col] = acc[i][j][r] + b;
            }
        }
}

// ---------------------------------------------------------------------------
extern "C" void kernel_launch(void* const* d_in, const int* in_sizes, int n_in,
                              void* d_out, int out_size, void* d_ws, size_t ws_size,
                              hipStream_t stream) {
    const float* Q   = (const float*)d_in[0];
    const float* K   = (const float*)d_in[1];
    const int*   nbr = (const int*)d_in[2];
    const float* Wq  = (const float*)d_in[3];
    const float* bq  = (const float*)d_in[4];
    const float* Wk  = (const float*)d_in[5];
    const float* bk  = (const float*)d_in[6];
    const float* Wv  = (const float*)d_in[7];
    const float* bv  = (const float*)d_in[8];
    const float* Wo  = (const float*)d_in[9];
    const float* bo  = (const float*)d_in[10];
    float* out = (float*)d_out;

    char* ws = (char*)d_ws;
    size_t off = 0;
    auto alloc = [&](size_t bytes) -> void* {
        void* p = ws + off;
        off += (bytes + 255) & ~(size_t)255;
        return p;
    };
    const size_t MN = 16384;  // B*N == B*M
    u16* Wtq = (u16*)alloc(256 * 256 * 2);
    u16* Wtk = (u16*)alloc(256 * 256 * 2);
    u16* Wtv = (u16*)alloc(256 * 256 * 2);
    u16* Wto = (u16*)alloc(256 * 256 * 2);
    u16* Qh  = (u16*)alloc(MN * 256 * 2);
    u16* Kh  = (u16*)alloc(MN * 256 * 2);
    u16* Vh  = (u16*)alloc(MN * 256 * 2);
    u16* AVb = (u16*)alloc(MN * 256 * 2);

    wprep<<<dim3(4, 4, 4), 256, 0, stream>>>(Wq, Wk, Wv, Wo, Wtq, Wtk, Wtv, Wto);
    gemm_proj<<<dim3(128, 2, 3), 256, 0, stream>>>(Q, K, Wtq, Wtk, Wtv,
                                                   bq, bk, bv, Qh, Kh, Vh);
    attn<<<dim3(16384), 256, 0, stream>>>(Qh, Kh, Vh, nbr, AVb);
    gemm_out<<<dim3(128, 2, 1), 256, 0, stream>>>(AVb, Wto, bo, out);
}

// Round 2
// 166.475 us; speedup vs baseline: 1.1918x; 1.1918x over previous
//
#include <hip/hip_runtime.h>
#include <stdint.h>

typedef unsigned short u16;
typedef __attribute__((ext_vector_type(8))) short short8;
typedef __attribute__((ext_vector_type(4))) float f32x4;

__device__ __forceinline__ float bf2f(u16 u) {
    union { unsigned int i; float f; } v;
    v.i = ((unsigned int)u) << 16;
    return v.f;
}
__device__ __forceinline__ u16 f2bf(float f) {
    union { float f; unsigned int i; } v; v.f = f;
    unsigned int b = v.i;
    return (u16)((b + 0x7FFFu + ((b >> 16) & 1u)) >> 16);
}

// async global->LDS, 16B per lane. LDS dest must be wave-uniform base; HW adds lane*16.
typedef const __attribute__((address_space(1))) void* as1cv;
typedef __attribute__((address_space(3))) void* as3v;
__device__ __forceinline__ void gload16(const void* g, void* l) {
    __builtin_amdgcn_global_load_lds((as1cv)g, (as3v)l, 16, 0, 0);
}

// ---------------------------------------------------------------------------
// Kernel 0: fp32 -> bf16 convert for Q and K (A operands of proj GEMMs)
// grid (2048, 2), block 256; 8 elems/thread
// ---------------------------------------------------------------------------
__global__ __launch_bounds__(256) void cvt(
    const float* __restrict__ Q, const float* __restrict__ K,
    u16* __restrict__ Qb, u16* __restrict__ Kb)
{
    const float* src = blockIdx.y ? K : Q;
    u16* dst = blockIdx.y ? Kb : Qb;
    size_t i = ((size_t)blockIdx.x * 256 + threadIdx.x) * 8;
    float4 a = *reinterpret_cast<const float4*>(src + i);
    float4 b = *reinterpret_cast<const float4*>(src + i + 4);
    u16 o[8] = {f2bf(a.x), f2bf(a.y), f2bf(a.z), f2bf(a.w),
                f2bf(b.x), f2bf(b.y), f2bf(b.z), f2bf(b.w)};
    *reinterpret_cast<uint4*>(dst + i) = *reinterpret_cast<const uint4*>(o);
}

// ---------------------------------------------------------------------------
// Kernel 1: weight convert fp32 -> bf16, transposed: Wt[n][k] = W[k][n]
// ---------------------------------------------------------------------------
__global__ __launch_bounds__(256) void wprep(
    const float* __restrict__ W0, const float* __restrict__ W1,
    const float* __restrict__ W2, const float* __restrict__ W3,
    u16* __restrict__ T0, u16* __restrict__ T1,
    u16* __restrict__ T2, u16* __restrict__ T3)
{
    const float* W = blockIdx.z == 0 ? W0 : blockIdx.z == 1 ? W1 : blockIdx.z == 2 ? W2 : W3;
    u16*        T  = blockIdx.z == 0 ? T0 : blockIdx.z == 1 ? T1 : blockIdx.z == 2 ? T2 : T3;
    __shared__ u16 ts[64][65];
    int k0 = blockIdx.x * 64, n0 = blockIdx.y * 64;
    int t = threadIdx.x;
    int r = t >> 2, cq = (t & 3) * 16;
    const float4* src = reinterpret_cast<const float4*>(W + (k0 + r) * 256 + n0 + cq);
    for (int u = 0; u < 4; ++u) {
        float4 v = src[u];
        int c = cq + u * 4;
        ts[r][c + 0] = f2bf(v.x); ts[r][c + 1] = f2bf(v.y);
        ts[r][c + 2] = f2bf(v.z); ts[r][c + 3] = f2bf(v.w);
    }
    __syncthreads();
    u16* dst = T + (n0 + r) * 256 + k0 + cq;
    for (int u = 0; u < 16; ++u) dst[u] = ts[cq + u][r];
}

// ---------------------------------------------------------------------------
// GEMM core: bf16 A [16384,256] @ Wt[n][k] bf16 + bias -> C (bf16 or f32)
// 128x128 tile, BK=64, global_load_lds x16B staging, unpadded LDS (required
// by the wave-uniform-base scatter rule of global_load_lds).
// ---------------------------------------------------------------------------
template <bool F32OUT>
__device__ __forceinline__ void gemm_core(
    const u16* __restrict__ Ab, const u16* __restrict__ Wt,
    const float* __restrict__ bias, void* __restrict__ Cv,
    int row0, int col0)
{
    __shared__ u16 As[128 * 64];
    __shared__ u16 Bs[128 * 64];

    int t = threadIdx.x;
    int lane = t & 63, w = t >> 6;
    int wr = (w >> 1) * 64, wc = (w & 1) * 64;
    int qd = lane >> 4, md = lane & 15;

    // staging map: chunk = w*4+u covers LDS bytes [chunk*1024, +1024)
    // lane covers 16B -> row = chunk*8 + lane/8, kcol = (lane&7)*8 elems
    int srow = w * 32 + (lane >> 3);
    int scol = (lane & 7) * 8;

    f32x4 acc[4][4] = {};

    for (int kt = 0; kt < 256; kt += 64) {
#pragma unroll
        for (int u = 0; u < 4; ++u) {
            int r = srow + u * 8;
            gload16(Ab + (size_t)(row0 + r) * 256 + kt + scol,
                    (char*)As + (w * 4 + u) * 1024);
            gload16(Wt + (size_t)(col0 + r) * 256 + kt + scol,
                    (char*)Bs + (w * 4 + u) * 1024);
        }
        __syncthreads();
#pragma unroll
        for (int ks = 0; ks < 64; ks += 32) {
            short8 af[4], bf[4];
#pragma unroll
            for (int i = 0; i < 4; ++i)
                af[i] = *reinterpret_cast<const short8*>(
                    &As[(wr + i * 16 + md) * 64 + ks + qd * 8]);
#pragma unroll
            for (int j = 0; j < 4; ++j)
                bf[j] = *reinterpret_cast<const short8*>(
                    &Bs[(wc + j * 16 + md) * 64 + ks + qd * 8]);
#pragma unroll
            for (int i = 0; i < 4; ++i)
#pragma unroll
                for (int j = 0; j < 4; ++j)
                    acc[i][j] = __builtin_amdgcn_mfma_f32_16x16x32_bf16(
                        af[i], bf[j], acc[i][j], 0, 0, 0);
        }
        __syncthreads();
    }

#pragma unroll
    for (int i = 0; i < 4; ++i)
#pragma unroll
        for (int j = 0; j < 4; ++j) {
            int col = col0 + wc + j * 16 + md;
            float b = bias[col];
#pragma unroll
            for (int r = 0; r < 4; ++r) {
                int row = row0 + wr + i * 16 + qd * 4 + r;
                if (F32OUT)
                    ((float*)Cv)[(size_t)row * 256 + col] = acc[i][j][r] + b;
                else
                    ((u16*)Cv)[(size_t)row * 256 + col] = f2bf(acc[i][j][r] + b);
            }
        }
}

__global__ __launch_bounds__(256) void gemm_proj(
    const u16* __restrict__ Qb, const u16* __restrict__ Kb,
    const u16* __restrict__ Wtq, const u16* __restrict__ Wtk, const u16* __restrict__ Wtv,
    const float* __restrict__ bq, const float* __restrict__ bk, const float* __restrict__ bv,
    u16* __restrict__ Qh, u16* __restrict__ Kh, u16* __restrict__ Vh)
{
    int z = blockIdx.z;
    const u16*   A    = (z == 0) ? Qb  : Kb;
    const u16*   Wt   = (z == 0) ? Wtq : (z == 1) ? Wtk : Wtv;
    const float* bias = (z == 0) ? bq  : (z == 1) ? bk  : bv;
    u16*         C    = (z == 0) ? Qh  : (z == 1) ? Kh  : Vh;
    gemm_core<false>(A, Wt, bias, C, blockIdx.x * 128, blockIdx.y * 128);
}

__global__ __launch_bounds__(256) void gemm_out(
    const u16* __restrict__ A, const u16* __restrict__ Wt,
    const float* __restrict__ bias, float* __restrict__ Cout)
{
    gemm_core<true>(A, Wt, bias, Cout, blockIdx.x * 128, blockIdx.y * 128);
}

// ---------------------------------------------------------------------------
// Kernel 3: gather attention. One block (256 thr) per (b,n).
// K staged in LDS (coalesced row gather); V streamed from global in the AV
// loop (reads are coalesced per neighbour anyway). LDS ~19 KB -> 8 blocks/CU.
// ---------------------------------------------------------------------------
__global__ __launch_bounds__(256) void attn(
    const u16* __restrict__ Qh, const u16* __restrict__ Kh, const u16* __restrict__ Vh,
    const int* __restrict__ nbr, u16* __restrict__ AVb)
{
    __shared__ u16 Ks[32][264];   // 528B stride: 16B-aligned, breaks 512B bank stride
    __shared__ float qs[256];
    __shared__ float as_[256];
    __shared__ int ji[32];

    int t = threadIdx.x;
    int row = blockIdx.x;             // b*8192 + n
    int b = row >> 13;
    size_t qbase = (size_t)row * 256;

    qs[t] = bf2f(Qh[qbase + t]);
    if (t < 32) ji[t] = nbr[(size_t)row * 32 + t];
    __syncthreads();

    // gather 32 K rows (512 B each) into LDS: 8 threads/row x 64 B
    {
        int j = t >> 3, seg = t & 7;
        size_t kb = (((size_t)b << 13) + (size_t)ji[j]) * 256;
        const uint4* ksrc = reinterpret_cast<const uint4*>(Kh + kb);
        uint4* kdst = reinterpret_cast<uint4*>(&Ks[j][seg * 32]);
        kdst[0] = ksrc[seg * 4 + 0]; kdst[1] = ksrc[seg * 4 + 1];
        kdst[2] = ksrc[seg * 4 + 2]; kdst[3] = ksrc[seg * 4 + 3];
    }
    __syncthreads();

    // scores: thread t -> (h = t>>5, j = t&31)
    int h = t >> 5, j = t & 31;
    float e = 0.f;
#pragma unroll
    for (int c = 0; c < 4; ++c) {
        short8 kv = *reinterpret_cast<const short8*>(&Ks[j][h * 32 + c * 8]);
#pragma unroll
        for (int u = 0; u < 8; ++u)
            e += qs[h * 32 + c * 8 + u] * bf2f((u16)kv[u]);
    }
    e *= 0.0625f;  // 1/sqrt(256)

    float m = e;
    for (int off = 16; off; off >>= 1) m = fmaxf(m, __shfl_xor(m, off, 32));
    float p = __expf(e - m);
    float s = p;
    for (int off = 16; off; off >>= 1) s += __shfl_xor(s, off, 32);
    as_[t] = p / s;
    __syncthreads();

    // AV: thread t -> output channel t; stream V rows from global (coalesced:
    // for fixed jj, 256 threads read 512 contiguous bytes). 32 indep loads.
    int hh = t >> 5;
    float acc = 0.f;
    size_t vbase = ((size_t)b << 13) * 256;
#pragma unroll
    for (int jj = 0; jj < 32; ++jj) {
        float wgt = as_[hh * 32 + jj];
        acc += wgt * bf2f(Vh[vbase + (size_t)ji[jj] * 256 + t]);
    }
    AVb[qbase + t] = f2bf(acc);
}

// ---------------------------------------------------------------------------
extern "C" void kernel_launch(void* const* d_in, const int* in_sizes, int n_in,
                              void* d_out, int out_size, void* d_ws, size_t ws_size,
                              hipStream_t stream) {
    const float* Q   = (const float*)d_in[0];
    const float* K   = (const float*)d_in[1];
    const int*   nbr = (const int*)d_in[2];
    const float* Wq  = (const float*)d_in[3];
    const float* bq  = (const float*)d_in[4];
    const float* Wk  = (const float*)d_in[5];
    const float* bk  = (const float*)d_in[6];
    const float* Wv  = (const float*)d_in[7];
    const float* bv  = (const float*)d_in[8];
    const float* Wo  = (const float*)d_in[9];
    const float* bo  = (const float*)d_in[10];
    float* out = (float*)d_out;

    char* ws = (char*)d_ws;
    size_t off = 0;
    auto alloc = [&](size_t bytes) -> void* {
        void* p = ws + off;
        off += (bytes + 255) & ~(size_t)255;
        return p;
    };
    const size_t MN = 16384;  // B*N == B*M
    u16* Wtq = (u16*)alloc(256 * 256 * 2);
    u16* Wtk = (u16*)alloc(256 * 256 * 2);
    u16* Wtv = (u16*)alloc(256 * 256 * 2);
    u16* Wto = (u16*)alloc(256 * 256 * 2);
    u16* Qb  = (u16*)alloc(MN * 256 * 2);
    u16* Kb  = (u16*)alloc(MN * 256 * 2);
    u16* Qh  = (u16*)alloc(MN * 256 * 2);
    u16* Kh  = (u16*)alloc(MN * 256 * 2);
    u16* Vh  = (u16*)alloc(MN * 256 * 2);
    u16* AVb = (u16*)alloc(MN * 256 * 2);

    cvt<<<dim3(2048, 2), 256, 0, stream>>>(Q, K, Qb, Kb);
    wprep<<<dim3(4, 4, 4), 256, 0, stream>>>(Wq, Wk, Wv, Wo, Wtq, Wtk, Wtv, Wto);
    gemm_proj<<<dim3(128, 2, 3), 256, 0, stream>>>(Qb, Kb, Wtq, Wtk, Wtv,
                                                   bq, bk, bv, Qh, Kh, Vh);
    attn<<<dim3(16384), 256, 0, stream>>>(Qh, Kh, Vh, nbr, AVb);
    gemm_out<<<dim3(128, 2, 1), 256, 0, stream>>>(AVb, Wto, bo, out);
}